// Round 1
// baseline (1651.533 us; speedup 1.0000x reference)
//
#include <hip/hip_runtime.h>
#include <math.h>

#define DD 128
#define TILE 32
#define KCH 32
#define NEG 0.01f

__device__ __forceinline__ float lrelu(float x){ return x > 0.f ? x : NEG * x; }

// monotonic float -> uint encoding (order-preserving for non-NaN)
__device__ __forceinline__ unsigned enc_f(float f){
    unsigned u = __float_as_uint(f);
    return (u & 0x80000000u) ? ~u : (u | 0x80000000u);
}
__device__ __forceinline__ float dec_f(unsigned k){
    unsigned u = (k & 0x80000000u) ? (k & 0x7fffffffu) : ~k;
    return __uint_as_float(u);
}

__global__ void init_kernel(float* nf, unsigned* mkey, float* denom, int n_dst){
    int i = blockIdx.x * blockDim.x + threadIdx.x;
    if (i < n_dst * DD) nf[i] = 0.f;
    if (i < n_dst){ mkey[i] = 0u; denom[i] = 0.f; }
}

// Y[r][c] = act(X[r] . W[:,c] + b[c]); 32 rows x 128 cols per block.
// Thread (cq=tid&31, rs=tid>>5) owns cols 4cq..4cq+3 of rows 4rs..4rs+3.
// Safe for in-place X==Y: each block reads only the rows it writes, writes last.
__global__ __launch_bounds__(256) void tiled_linear(const float* X, const float* W,
                                                    const float* b, float* Y,
                                                    int nrows, int do_act){
    __shared__ float sW[KCH][DD];   // 16 KB
    __shared__ float sX[TILE][36];  // padded stride 36 (bank spread + 16B align)
    const int tid = threadIdx.x;
    const int cq = tid & 31, rs = tid >> 5;
    const int row0 = blockIdx.x * TILE;
    float acc[4][4] = {};
    for (int kk = 0; kk < DD; kk += KCH){
        const float4* Wv = (const float4*)(W + (size_t)kk * DD);
        float4* sWv = (float4*)(&sW[0][0]);
        #pragma unroll
        for (int t = 0; t < 4; t++) sWv[tid + 256 * t] = Wv[tid + 256 * t];
        {
            int r = tid >> 3, j = (tid & 7) << 2;
            int row = row0 + r;
            float4 v = make_float4(0.f, 0.f, 0.f, 0.f);
            if (row < nrows) v = *(const float4*)(X + (size_t)row * DD + kk + j);
            sX[r][j] = v.x; sX[r][j + 1] = v.y; sX[r][j + 2] = v.z; sX[r][j + 3] = v.w;
        }
        __syncthreads();
        #pragma unroll
        for (int k = 0; k < KCH; k += 4){
            float t4[4][4];
            #pragma unroll
            for (int e = 0; e < 4; e++)
                *(float4*)t4[e] = *(const float4*)&sX[rs * 4 + e][k];
            #pragma unroll
            for (int kq = 0; kq < 4; kq++){
                float4 w4 = *(const float4*)&sW[k + kq][cq * 4];
                #pragma unroll
                for (int e = 0; e < 4; e++){
                    acc[e][0] += t4[e][kq] * w4.x;
                    acc[e][1] += t4[e][kq] * w4.y;
                    acc[e][2] += t4[e][kq] * w4.z;
                    acc[e][3] += t4[e][kq] * w4.w;
                }
            }
        }
        __syncthreads();
    }
    float4 bv = *(const float4*)(b + cq * 4);
    #pragma unroll
    for (int e = 0; e < 4; e++){
        int row = row0 + rs * 4 + e;
        if (row < nrows){
            float4 y;
            y.x = acc[e][0] + bv.x; y.y = acc[e][1] + bv.y;
            y.z = acc[e][2] + bv.z; y.w = acc[e][3] + bv.w;
            if (do_act){ y.x = lrelu(y.x); y.y = lrelu(y.y); y.z = lrelu(y.z); y.w = lrelu(y.w); }
            *(float4*)(Y + (size_t)row * DD + cq * 4) = y;
        }
    }
}

// Per-edge attention score: sc[e] = lrelu(lrelu(hs[src]+hd[dst]) @ Wa1 + ba1) . Wa2 + ba2
// Same tiling as tiled_linear; 32 edges per block.
__global__ __launch_bounds__(256) void edge_score(const float* hs, const float* hd,
        const int* src, const int* dst, const float* Wa1, const float* ba1,
        const float* Wa2, const float* ba2, float* sc, int E){
    __shared__ float sW[KCH][DD];
    __shared__ float sT[TILE][36];
    const int tid = threadIdx.x;
    const int cq = tid & 31, rs = tid >> 5;
    const int e0 = blockIdx.x * TILE;
    float acc[4][4] = {};
    for (int kk = 0; kk < DD; kk += KCH){
        const float4* Wv = (const float4*)(Wa1 + (size_t)kk * DD);
        float4* sWv = (float4*)(&sW[0][0]);
        #pragma unroll
        for (int t = 0; t < 4; t++) sWv[tid + 256 * t] = Wv[tid + 256 * t];
        {
            int r = tid >> 3, j = (tid & 7) << 2;
            int eid = e0 + r; if (eid >= E) eid = E - 1;
            int s = src[eid], d = dst[eid];
            float4 a = *(const float4*)(hs + (size_t)s * DD + kk + j);
            float4 bb = *(const float4*)(hd + (size_t)d * DD + kk + j);
            sT[r][j]     = lrelu(a.x + bb.x);
            sT[r][j + 1] = lrelu(a.y + bb.y);
            sT[r][j + 2] = lrelu(a.z + bb.z);
            sT[r][j + 3] = lrelu(a.w + bb.w);
        }
        __syncthreads();
        #pragma unroll
        for (int k = 0; k < KCH; k += 4){
            float t4[4][4];
            #pragma unroll
            for (int e = 0; e < 4; e++)
                *(float4*)t4[e] = *(const float4*)&sT[rs * 4 + e][k];
            #pragma unroll
            for (int kq = 0; kq < 4; kq++){
                float4 w4 = *(const float4*)&sW[k + kq][cq * 4];
                #pragma unroll
                for (int e = 0; e < 4; e++){
                    acc[e][0] += t4[e][kq] * w4.x;
                    acc[e][1] += t4[e][kq] * w4.y;
                    acc[e][2] += t4[e][kq] * w4.z;
                    acc[e][3] += t4[e][kq] * w4.w;
                }
            }
        }
        __syncthreads();
    }
    float4 w2 = *(const float4*)(Wa2 + cq * 4);
    float4 b1 = *(const float4*)(ba1 + cq * 4);
    float b2 = ba2[0];
    #pragma unroll
    for (int e = 0; e < 4; e++){
        float p = lrelu(acc[e][0] + b1.x) * w2.x
                + lrelu(acc[e][1] + b1.y) * w2.y
                + lrelu(acc[e][2] + b1.z) * w2.z
                + lrelu(acc[e][3] + b1.w) * w2.w;
        #pragma unroll
        for (int off = 16; off > 0; off >>= 1) p += __shfl_down(p, off, 32);
        int eid = e0 + rs * 4 + e;
        if (cq == 0 && eid < E) sc[eid] = p + b2;
    }
}

__global__ void seg_max(const float* sc, const int* dst, unsigned* mkey, int E){
    int i = blockIdx.x * blockDim.x + threadIdx.x;
    if (i < E) atomicMax(&mkey[dst[i]], enc_f(sc[i]));
}

__global__ void seg_exp(const float* sc, const int* dst, const unsigned* mkey,
                        float* ex, float* denom, int E){
    int i = blockIdx.x * blockDim.x + threadIdx.x;
    if (i < E){
        int d = dst[i];
        float v = expf(sc[i] - dec_f(mkey[d]));
        ex[i] = v;
        atomicAdd(&denom[d], v);
    }
}

// nf[dst] += alpha * (hs[src] + hd[dst]); 8 edges/block, 32 lanes x 4 cols each
__global__ __launch_bounds__(256) void aggregate(const float* hs, const float* hd,
        const int* src, const int* dst, const float* ex, const float* denom,
        float* nf, int E){
    const int tid = threadIdx.x;
    const int le = tid >> 5, cq = tid & 31;
    const int eid = blockIdx.x * 8 + le;
    if (eid >= E) return;
    const int s = src[eid], d = dst[eid];
    const float alpha = ex[eid] / denom[d];
    float4 a = *(const float4*)(hs + (size_t)s * DD + cq * 4);
    float4 b = *(const float4*)(hd + (size_t)d * DD + cq * 4);
    float* out = nf + (size_t)d * DD + cq * 4;
    atomicAdd(out + 0, alpha * (a.x + b.x));
    atomicAdd(out + 1, alpha * (a.y + b.y));
    atomicAdd(out + 2, alpha * (a.z + b.z));
    atomicAdd(out + 3, alpha * (a.w + b.w));
}

extern "C" void kernel_launch(void* const* d_in, const int* in_sizes, int n_in,
                              void* d_out, int out_size, void* d_ws, size_t ws_size,
                              hipStream_t stream){
    const float* feat_src = (const float*)d_in[0];
    const float* feat_dst = (const float*)d_in[1];
    const int*   src_idx  = (const int*)d_in[2];
    const int*   dst_idx  = (const int*)d_in[3];
    const float* W_src = (const float*)d_in[4];
    const float* b_src = (const float*)d_in[5];
    const float* W_dst = (const float*)d_in[6];
    const float* b_dst = (const float*)d_in[7];
    const float* W_a1  = (const float*)d_in[8];
    const float* b_a1  = (const float*)d_in[9];
    const float* W_a2  = (const float*)d_in[10];
    const float* b_a2  = (const float*)d_in[11];
    const float* W_out = (const float*)d_in[12];
    const float* b_out = (const float*)d_in[13];
    const int n_src = in_sizes[0] / DD;
    const int n_dst = in_sizes[1] / DD;
    const int E = in_sizes[2];

    float* ws = (float*)d_ws;
    float* hs = ws;                                   // n_src*128
    float* hd = hs + (size_t)n_src * DD;              // n_dst*128
    float* sc = hd + (size_t)n_dst * DD;              // E
    float* ex = sc + E;                               // E
    unsigned* mkey = (unsigned*)(ex + E);             // n_dst
    float* denom = (float*)(mkey + n_dst);            // n_dst
    float* nf = (float*)d_out;                        // n_dst*128 (accumulated in-place)

    init_kernel<<<(n_dst * DD + 255) / 256, 256, 0, stream>>>(nf, mkey, denom, n_dst);
    tiled_linear<<<(n_src + TILE - 1) / TILE, 256, 0, stream>>>(feat_src, W_src, b_src, hs, n_src, 0);
    tiled_linear<<<(n_dst + TILE - 1) / TILE, 256, 0, stream>>>(feat_dst, W_dst, b_dst, hd, n_dst, 0);
    edge_score<<<(E + TILE - 1) / TILE, 256, 0, stream>>>(hs, hd, src_idx, dst_idx,
                                                          W_a1, b_a1, W_a2, b_a2, sc, E);
    seg_max<<<(E + 255) / 256, 256, 0, stream>>>(sc, dst_idx, mkey, E);
    seg_exp<<<(E + 255) / 256, 256, 0, stream>>>(sc, dst_idx, mkey, ex, denom, E);
    aggregate<<<(E + 7) / 8, 256, 0, stream>>>(hs, hd, src_idx, dst_idx, ex, denom, nf, E);
    tiled_linear<<<(n_dst + TILE - 1) / TILE, 256, 0, stream>>>(nf, W_out, b_out, nf, n_dst, 1);
}

// Round 2
// 731.315 us; speedup vs baseline: 2.2583x; 2.2583x over previous
//
#include <hip/hip_runtime.h>
#include <math.h>

#define DD 128
#define TILE 32
#define KCH 32
#define NEG 0.01f

__device__ __forceinline__ float lrelu(float x){ return x > 0.f ? x : NEG * x; }

// monotonic float -> uint encoding (order-preserving for non-NaN)
__device__ __forceinline__ unsigned enc_f(float f){
    unsigned u = __float_as_uint(f);
    return (u & 0x80000000u) ? ~u : (u | 0x80000000u);
}
__device__ __forceinline__ float dec_f(unsigned k){
    unsigned u = (k & 0x80000000u) ? (k & 0x7fffffffu) : ~k;
    return __uint_as_float(u);
}

__global__ void init_kernel(unsigned* mkey, float* denom, int* deg, int n_dst){
    int i = blockIdx.x * blockDim.x + threadIdx.x;
    if (i < n_dst){ mkey[i] = 0u; denom[i] = 0.f; deg[i] = 0; }
}

// Y[r][c] = act(X[r] . W[:,c] + b[c]); 32 rows x 128 cols per block.
// Safe for in-place X==Y: each block reads only the rows it writes, writes last.
__global__ __launch_bounds__(256) void tiled_linear(const float* X, const float* W,
                                                    const float* b, float* Y,
                                                    int nrows, int do_act){
    __shared__ float sW[KCH][DD];   // 16 KB
    __shared__ float sX[TILE][36];  // padded stride 36
    const int tid = threadIdx.x;
    const int cq = tid & 31, rs = tid >> 5;
    const int row0 = blockIdx.x * TILE;
    float acc[4][4] = {};
    for (int kk = 0; kk < DD; kk += KCH){
        const float4* Wv = (const float4*)(W + (size_t)kk * DD);
        float4* sWv = (float4*)(&sW[0][0]);
        #pragma unroll
        for (int t = 0; t < 4; t++) sWv[tid + 256 * t] = Wv[tid + 256 * t];
        {
            int r = tid >> 3, j = (tid & 7) << 2;
            int row = row0 + r;
            float4 v = make_float4(0.f, 0.f, 0.f, 0.f);
            if (row < nrows) v = *(const float4*)(X + (size_t)row * DD + kk + j);
            sX[r][j] = v.x; sX[r][j + 1] = v.y; sX[r][j + 2] = v.z; sX[r][j + 3] = v.w;
        }
        __syncthreads();
        #pragma unroll
        for (int k = 0; k < KCH; k += 4){
            float t4[4][4];
            #pragma unroll
            for (int e = 0; e < 4; e++)
                *(float4*)t4[e] = *(const float4*)&sX[rs * 4 + e][k];
            #pragma unroll
            for (int kq = 0; kq < 4; kq++){
                float4 w4 = *(const float4*)&sW[k + kq][cq * 4];
                #pragma unroll
                for (int e = 0; e < 4; e++){
                    acc[e][0] += t4[e][kq] * w4.x;
                    acc[e][1] += t4[e][kq] * w4.y;
                    acc[e][2] += t4[e][kq] * w4.z;
                    acc[e][3] += t4[e][kq] * w4.w;
                }
            }
        }
        __syncthreads();
    }
    float4 bv = *(const float4*)(b + cq * 4);
    #pragma unroll
    for (int e = 0; e < 4; e++){
        int row = row0 + rs * 4 + e;
        if (row < nrows){
            float4 y;
            y.x = acc[e][0] + bv.x; y.y = acc[e][1] + bv.y;
            y.z = acc[e][2] + bv.z; y.w = acc[e][3] + bv.w;
            if (do_act){ y.x = lrelu(y.x); y.y = lrelu(y.y); y.z = lrelu(y.z); y.w = lrelu(y.w); }
            *(float4*)(Y + (size_t)row * DD + cq * 4) = y;
        }
    }
}

// Per-edge attention score: sc[e] = lrelu(lrelu(hs[src]+hd[dst]) @ Wa1 + ba1) . Wa2 + ba2
__global__ __launch_bounds__(256) void edge_score(const float* hs, const float* hd,
        const int* src, const int* dst, const float* Wa1, const float* ba1,
        const float* Wa2, const float* ba2, float* sc, int E){
    __shared__ float sW[KCH][DD];
    __shared__ float sT[TILE][36];
    const int tid = threadIdx.x;
    const int cq = tid & 31, rs = tid >> 5;
    const int e0 = blockIdx.x * TILE;
    float acc[4][4] = {};
    for (int kk = 0; kk < DD; kk += KCH){
        const float4* Wv = (const float4*)(Wa1 + (size_t)kk * DD);
        float4* sWv = (float4*)(&sW[0][0]);
        #pragma unroll
        for (int t = 0; t < 4; t++) sWv[tid + 256 * t] = Wv[tid + 256 * t];
        {
            int r = tid >> 3, j = (tid & 7) << 2;
            int eid = e0 + r; if (eid >= E) eid = E - 1;
            int s = src[eid], d = dst[eid];
            float4 a = *(const float4*)(hs + (size_t)s * DD + kk + j);
            float4 bb = *(const float4*)(hd + (size_t)d * DD + kk + j);
            sT[r][j]     = lrelu(a.x + bb.x);
            sT[r][j + 1] = lrelu(a.y + bb.y);
            sT[r][j + 2] = lrelu(a.z + bb.z);
            sT[r][j + 3] = lrelu(a.w + bb.w);
        }
        __syncthreads();
        #pragma unroll
        for (int k = 0; k < KCH; k += 4){
            float t4[4][4];
            #pragma unroll
            for (int e = 0; e < 4; e++)
                *(float4*)t4[e] = *(const float4*)&sT[rs * 4 + e][k];
            #pragma unroll
            for (int kq = 0; kq < 4; kq++){
                float4 w4 = *(const float4*)&sW[k + kq][cq * 4];
                #pragma unroll
                for (int e = 0; e < 4; e++){
                    acc[e][0] += t4[e][kq] * w4.x;
                    acc[e][1] += t4[e][kq] * w4.y;
                    acc[e][2] += t4[e][kq] * w4.z;
                    acc[e][3] += t4[e][kq] * w4.w;
                }
            }
        }
        __syncthreads();
    }
    float4 w2 = *(const float4*)(Wa2 + cq * 4);
    float4 b1 = *(const float4*)(ba1 + cq * 4);
    float b2 = ba2[0];
    #pragma unroll
    for (int e = 0; e < 4; e++){
        float p = lrelu(acc[e][0] + b1.x) * w2.x
                + lrelu(acc[e][1] + b1.y) * w2.y
                + lrelu(acc[e][2] + b1.z) * w2.z
                + lrelu(acc[e][3] + b1.w) * w2.w;
        #pragma unroll
        for (int off = 16; off > 0; off >>= 1) p += __shfl_down(p, off, 32);
        int eid = e0 + rs * 4 + e;
        if (cq == 0 && eid < E) sc[eid] = p + b2;
    }
}

__global__ void hist_kernel(const int* dst, int* deg, int E){
    int i = blockIdx.x * blockDim.x + threadIdx.x;
    if (i < E) atomicAdd(&deg[dst[i]], 1);
}

// single-block exclusive scan of deg[0..n) -> row_off[0..n], row_off[n]=total.
// Also copies offsets into cursor[] for the scatter pass.
__global__ __launch_bounds__(1024) void scan_kernel(const int* deg, int* row_off,
                                                    int* cursor, int n){
    __shared__ int wsum[16];
    const int tid = threadIdx.x;
    const int lane = tid & 63, wid = tid >> 6;
    int carry = 0;
    for (int base = 0; base < n; base += 1024){
        int i = base + tid;
        int v = (i < n) ? deg[i] : 0;
        // inclusive scan within wave
        int x = v;
        #pragma unroll
        for (int off = 1; off < 64; off <<= 1){
            int t = __shfl_up(x, off, 64);
            if (lane >= off) x += t;
        }
        if (lane == 63) wsum[wid] = x;
        __syncthreads();
        int wprefix = 0, total = 0;
        #pragma unroll
        for (int j = 0; j < 16; j++){
            int s = wsum[j];
            if (j < wid) wprefix += s;
            total += s;
        }
        int excl = carry + wprefix + (x - v);
        if (i < n){ row_off[i] = excl; cursor[i] = excl; }
        carry += total;
        __syncthreads();
    }
    if (tid == 0) row_off[n] = carry;
}

__global__ void seg_max(const float* sc, const int* dst, unsigned* mkey, int E){
    int i = blockIdx.x * blockDim.x + threadIdx.x;
    if (i < E) atomicMax(&mkey[dst[i]], enc_f(sc[i]));
}

__global__ void seg_exp(const float* sc, const int* dst, const unsigned* mkey,
                        float* ex, float* denom, int E){
    int i = blockIdx.x * blockDim.x + threadIdx.x;
    if (i < E){
        int d = dst[i];
        float v = expf(sc[i] - dec_f(mkey[d]));
        ex[i] = v;
        atomicAdd(&denom[d], v);
    }
}

// bucket edges by dst; store src index and final alpha per sorted slot
__global__ void scatter_kernel(const int* src, const int* dst, const float* ex,
                               const float* denom, int* cursor,
                               int* s_src, float* s_alpha, int E){
    int i = blockIdx.x * blockDim.x + threadIdx.x;
    if (i < E){
        int d = dst[i];
        int pos = atomicAdd(&cursor[d], 1);
        s_src[pos] = src[i];
        s_alpha[pos] = ex[i] / denom[d];
    }
}

// one wave per dst node: nf[n] = sum_e alpha_e * hs[src_e]  +  (sum_e alpha_e) * hd[n]
__global__ __launch_bounds__(256) void agg_csr(const float* hs, const float* hd,
        const int* row_off, const int* s_src, const float* s_alpha,
        float* nf, int n_dst){
    const int w = (blockIdx.x * blockDim.x + threadIdx.x) >> 6;
    const int lane = threadIdx.x & 63;
    if (w >= n_dst) return;
    const int beg = row_off[w], end = row_off[w + 1];
    float2 acc = make_float2(0.f, 0.f);
    float sa = 0.f;
    int e = beg;
    for (; e + 1 < end; e += 2){
        int s0 = s_src[e], s1 = s_src[e + 1];
        float a0 = s_alpha[e], a1 = s_alpha[e + 1];
        float2 v0 = *(const float2*)(hs + (size_t)s0 * DD + lane * 2);
        float2 v1 = *(const float2*)(hs + (size_t)s1 * DD + lane * 2);
        acc.x += a0 * v0.x + a1 * v1.x;
        acc.y += a0 * v0.y + a1 * v1.y;
        sa += a0 + a1;
    }
    if (e < end){
        int s0 = s_src[e];
        float a0 = s_alpha[e];
        float2 v0 = *(const float2*)(hs + (size_t)s0 * DD + lane * 2);
        acc.x += a0 * v0.x; acc.y += a0 * v0.y;
        sa += a0;
    }
    float2 h = *(const float2*)(hd + (size_t)w * DD + lane * 2);
    float2 out;
    out.x = acc.x + sa * h.x;
    out.y = acc.y + sa * h.y;
    *(float2*)(nf + (size_t)w * DD + lane * 2) = out;
}

extern "C" void kernel_launch(void* const* d_in, const int* in_sizes, int n_in,
                              void* d_out, int out_size, void* d_ws, size_t ws_size,
                              hipStream_t stream){
    const float* feat_src = (const float*)d_in[0];
    const float* feat_dst = (const float*)d_in[1];
    const int*   src_idx  = (const int*)d_in[2];
    const int*   dst_idx  = (const int*)d_in[3];
    const float* W_src = (const float*)d_in[4];
    const float* b_src = (const float*)d_in[5];
    const float* W_dst = (const float*)d_in[6];
    const float* b_dst = (const float*)d_in[7];
    const float* W_a1  = (const float*)d_in[8];
    const float* b_a1  = (const float*)d_in[9];
    const float* W_a2  = (const float*)d_in[10];
    const float* b_a2  = (const float*)d_in[11];
    const float* W_out = (const float*)d_in[12];
    const float* b_out = (const float*)d_in[13];
    const int n_src = in_sizes[0] / DD;
    const int n_dst = in_sizes[1] / DD;
    const int E = in_sizes[2];

    float* ws = (float*)d_ws;
    float* hs = ws;                                   // n_src*128
    float* hd = hs + (size_t)n_src * DD;              // n_dst*128
    float* sc = hd + (size_t)n_dst * DD;              // E  (reused as s_alpha after seg_exp)
    float* ex = sc + E;                               // E
    unsigned* mkey = (unsigned*)(ex + E);             // n_dst
    float* denom = (float*)(mkey + n_dst);            // n_dst
    int* deg    = (int*)(denom + n_dst);              // n_dst
    int* row_off = deg + n_dst;                       // n_dst+1
    int* cursor  = row_off + n_dst + 1;               // n_dst
    int* s_src   = cursor + n_dst;                    // E
    float* s_alpha = sc;                              // alias: sc dead after seg_exp
    float* nf = (float*)d_out;                        // n_dst*128

    init_kernel<<<(n_dst + 255) / 256, 256, 0, stream>>>(mkey, denom, deg, n_dst);
    hist_kernel<<<(E + 255) / 256, 256, 0, stream>>>(dst_idx, deg, E);
    scan_kernel<<<1, 1024, 0, stream>>>(deg, row_off, cursor, n_dst);
    tiled_linear<<<(n_src + TILE - 1) / TILE, 256, 0, stream>>>(feat_src, W_src, b_src, hs, n_src, 0);
    tiled_linear<<<(n_dst + TILE - 1) / TILE, 256, 0, stream>>>(feat_dst, W_dst, b_dst, hd, n_dst, 0);
    edge_score<<<(E + TILE - 1) / TILE, 256, 0, stream>>>(hs, hd, src_idx, dst_idx,
                                                          W_a1, b_a1, W_a2, b_a2, sc, E);
    seg_max<<<(E + 255) / 256, 256, 0, stream>>>(sc, dst_idx, mkey, E);
    seg_exp<<<(E + 255) / 256, 256, 0, stream>>>(sc, dst_idx, mkey, ex, denom, E);
    scatter_kernel<<<(E + 255) / 256, 256, 0, stream>>>(src_idx, dst_idx, ex, denom,
                                                        cursor, s_src, s_alpha, E);
    agg_csr<<<(n_dst * 64 + 255) / 256, 256, 0, stream>>>(hs, hd, row_off, s_src, s_alpha, nf, n_dst);
    tiled_linear<<<(n_dst + TILE - 1) / TILE, 256, 0, stream>>>(nf, W_out, b_out, nf, n_dst, 1);
}

// Round 3
// 520.744 us; speedup vs baseline: 3.1715x; 1.4044x over previous
//
#include <hip/hip_runtime.h>
#include <math.h>

#define DD 128
#define TILE 32
#define KCH 32
#define NEG 0.01f

typedef __attribute__((ext_vector_type(8))) short short8;
typedef __attribute__((ext_vector_type(4))) float f32x4;

__device__ __forceinline__ float lrelu(float x){ return x > 0.f ? x : NEG * x; }

// fp32 -> bf16 round-to-nearest-even (finite inputs)
__device__ __forceinline__ unsigned short f2bf(float f){
    unsigned u = __float_as_uint(f);
    u += 0x7fffu + ((u >> 16) & 1u);
    return (unsigned short)(u >> 16);
}
__device__ __forceinline__ float bf2f(unsigned short h){
    return __uint_as_float(((unsigned)h) << 16);
}

// monotonic float -> uint encoding (order-preserving for non-NaN)
__device__ __forceinline__ unsigned enc_f(float f){
    unsigned u = __float_as_uint(f);
    return (u & 0x80000000u) ? ~u : (u | 0x80000000u);
}
__device__ __forceinline__ float dec_f(unsigned k){
    unsigned u = (k & 0x80000000u) ? (k & 0x7fffffffu) : ~k;
    return __uint_as_float(u);
}

__global__ void init_kernel(unsigned* mkey, float* denom, int* deg, int n_dst){
    int i = blockIdx.x * blockDim.x + threadIdx.x;
    if (i < n_dst){ mkey[i] = 0u; denom[i] = 0.f; deg[i] = 0; }
}

// pack Wa1 (fp32 row-major [k][n]) into bf16 MFMA B-fragment-linear order:
// out[(((kc*8 + nt)*64 + lane)*8 + j)] = bf16(Wa1[(kc*32 + (lane>>4)*8 + j)*128 + nt*16 + (lane&15)])
__global__ void wa1_pack(const float* Wa1, unsigned short* out){
    int i = blockIdx.x * blockDim.x + threadIdx.x;   // 16384 threads
    if (i >= 16384) return;
    int j = i & 7, lane = (i >> 3) & 63, nt = (i >> 9) & 7, kc = i >> 12;
    int k = kc * 32 + (lane >> 4) * 8 + j;
    int n = nt * 16 + (lane & 15);
    out[i] = f2bf(Wa1[k * DD + n]);
}

// Y[r][c] = act(X[r] . W[:,c] + b[c]); 32 rows x 128 cols per block.
// Optionally writes a bf16 shadow copy to Yb. Safe for in-place X==Y.
__global__ __launch_bounds__(256) void tiled_linear(const float* X, const float* W,
                                                    const float* b, float* Y,
                                                    unsigned short* Yb,
                                                    int nrows, int do_act){
    __shared__ float sW[KCH][DD];
    __shared__ float sX[TILE][36];
    const int tid = threadIdx.x;
    const int cq = tid & 31, rs = tid >> 5;
    const int row0 = blockIdx.x * TILE;
    float acc[4][4] = {};
    for (int kk = 0; kk < DD; kk += KCH){
        const float4* Wv = (const float4*)(W + (size_t)kk * DD);
        float4* sWv = (float4*)(&sW[0][0]);
        #pragma unroll
        for (int t = 0; t < 4; t++) sWv[tid + 256 * t] = Wv[tid + 256 * t];
        {
            int r = tid >> 3, j = (tid & 7) << 2;
            int row = row0 + r;
            float4 v = make_float4(0.f, 0.f, 0.f, 0.f);
            if (row < nrows) v = *(const float4*)(X + (size_t)row * DD + kk + j);
            sX[r][j] = v.x; sX[r][j + 1] = v.y; sX[r][j + 2] = v.z; sX[r][j + 3] = v.w;
        }
        __syncthreads();
        #pragma unroll
        for (int k = 0; k < KCH; k += 4){
            float t4[4][4];
            #pragma unroll
            for (int e = 0; e < 4; e++)
                *(float4*)t4[e] = *(const float4*)&sX[rs * 4 + e][k];
            #pragma unroll
            for (int kq = 0; kq < 4; kq++){
                float4 w4 = *(const float4*)&sW[k + kq][cq * 4];
                #pragma unroll
                for (int e = 0; e < 4; e++){
                    acc[e][0] += t4[e][kq] * w4.x;
                    acc[e][1] += t4[e][kq] * w4.y;
                    acc[e][2] += t4[e][kq] * w4.z;
                    acc[e][3] += t4[e][kq] * w4.w;
                }
            }
        }
        __syncthreads();
    }
    float4 bv = *(const float4*)(b + cq * 4);
    #pragma unroll
    for (int e = 0; e < 4; e++){
        int row = row0 + rs * 4 + e;
        if (row < nrows){
            float4 y;
            y.x = acc[e][0] + bv.x; y.y = acc[e][1] + bv.y;
            y.z = acc[e][2] + bv.z; y.w = acc[e][3] + bv.w;
            if (do_act){ y.x = lrelu(y.x); y.y = lrelu(y.y); y.z = lrelu(y.z); y.w = lrelu(y.w); }
            *(float4*)(Y + (size_t)row * DD + cq * 4) = y;
            if (Yb){
                ushort4 yb;
                yb.x = f2bf(y.x); yb.y = f2bf(y.y); yb.z = f2bf(y.z); yb.w = f2bf(y.w);
                *(ushort4*)(Yb + (size_t)row * DD + cq * 4) = yb;
            }
        }
    }
}

// build A-fragment: 8 bf16 of lrelu(hs_row + hd_row) at 16B-aligned offset
__device__ __forceinline__ short8 make_afrag(const unsigned short* ph, const unsigned short* pd){
    uint4 a = *(const uint4*)ph;
    uint4 b = *(const uint4*)pd;
    unsigned au[4] = {a.x, a.y, a.z, a.w};
    unsigned bu[4] = {b.x, b.y, b.z, b.w};
    short8 r;
    #pragma unroll
    for (int i = 0; i < 4; i++){
        float h0 = __uint_as_float(au[i] << 16);
        float h1 = __uint_as_float(au[i] & 0xffff0000u);
        float g0 = __uint_as_float(bu[i] << 16);
        float g1 = __uint_as_float(bu[i] & 0xffff0000u);
        float e0 = lrelu(h0 + g0);
        float e1 = lrelu(h1 + g1);
        r[2 * i]     = (short)f2bf(e0);
        r[2 * i + 1] = (short)f2bf(e1);
    }
    return r;
}

// MFMA edge attention score. 128 edges/block (4 waves x 32 edges).
// sc[e] = lrelu(lrelu(hs[src]+hd[dst]) @ Wa1 + ba1) . Wa2 + ba2
__global__ __launch_bounds__(256) void edge_score_mfma(
        const unsigned short* hs_b, const unsigned short* hd_b,
        const int* src, const int* dst,
        const unsigned short* wa1p, const float* ba1,
        const float* Wa2, const float* ba2, float* sc, int E){
    __shared__ unsigned short sB[16384];  // 32 KB packed B-fragments
    const int tid = threadIdx.x;
    {   // stage packed Wa1: 256 threads x 8 x 16B
        const uint4* g = (const uint4*)wa1p;
        uint4* l = (uint4*)sB;
        #pragma unroll
        for (int t = 0; t < 8; t++) l[tid + 256 * t] = g[tid + 256 * t];
    }
    const int wave = tid >> 6, lane = tid & 63;
    const int qd = lane >> 4, ln16 = lane & 15;
    const int e0 = blockIdx.x * 128 + wave * 32;
    int eid0 = e0 + ln16;       if (eid0 >= E) eid0 = E - 1;
    int eid1 = e0 + 16 + ln16;  if (eid1 >= E) eid1 = E - 1;
    const int s0 = src[eid0], d0 = dst[eid0];
    const int s1 = src[eid1], d1 = dst[eid1];
    f32x4 acc[2][8];
    #pragma unroll
    for (int rt = 0; rt < 2; rt++)
        #pragma unroll
        for (int nt = 0; nt < 8; nt++)
            acc[rt][nt] = (f32x4){0.f, 0.f, 0.f, 0.f};
    __syncthreads();
    #pragma unroll
    for (int kc = 0; kc < 4; kc++){
        const int koff = kc * 32 + qd * 8;
        short8 af0 = make_afrag(hs_b + (size_t)s0 * DD + koff, hd_b + (size_t)d0 * DD + koff);
        short8 af1 = make_afrag(hs_b + (size_t)s1 * DD + koff, hd_b + (size_t)d1 * DD + koff);
        #pragma unroll
        for (int nt = 0; nt < 8; nt++){
            short8 bf = *(const short8*)&sB[(((kc << 3) + nt) << 6 | lane) << 3];
            acc[0][nt] = __builtin_amdgcn_mfma_f32_16x16x32_bf16(af0, bf, acc[0][nt], 0, 0, 0);
            acc[1][nt] = __builtin_amdgcn_mfma_f32_16x16x32_bf16(af1, bf, acc[1][nt], 0, 0, 0);
        }
    }
    // epilogue in fp32: z = lrelu(acc + ba1[n]); partial = z * Wa2[n]; reduce over n
    float b1v[8], w2v[8];
    #pragma unroll
    for (int nt = 0; nt < 8; nt++){
        b1v[nt] = ba1[nt * 16 + ln16];
        w2v[nt] = Wa2[nt * 16 + ln16];
    }
    const float b2 = ba2[0];
    #pragma unroll
    for (int rt = 0; rt < 2; rt++){
        float p[4] = {0.f, 0.f, 0.f, 0.f};
        #pragma unroll
        for (int nt = 0; nt < 8; nt++)
            #pragma unroll
            for (int r = 0; r < 4; r++){
                float z = acc[rt][nt][r] + b1v[nt];
                z = z > 0.f ? z : NEG * z;
                p[r] += z * w2v[nt];
            }
        #pragma unroll
        for (int r = 0; r < 4; r++){
            float v = p[r];
            #pragma unroll
            for (int off = 1; off < 16; off <<= 1) v += __shfl_xor(v, off, 64);
            p[r] = v;
        }
        if (ln16 == 0){
            int row = e0 + rt * 16 + qd * 4;
            #pragma unroll
            for (int r = 0; r < 4; r++)
                if (row + r < E) sc[row + r] = p[r] + b2;
        }
    }
}

__global__ void hist_kernel(const int* dst, int* deg, int E){
    int i = blockIdx.x * blockDim.x + threadIdx.x;
    if (i < E) atomicAdd(&deg[dst[i]], 1);
}

// single-block exclusive scan of deg[0..n) -> row_off[0..n], row_off[n]=total.
__global__ __launch_bounds__(1024) void scan_kernel(const int* deg, int* row_off,
                                                    int* cursor, int n){
    __shared__ int wsum[16];
    const int tid = threadIdx.x;
    const int lane = tid & 63, wid = tid >> 6;
    int carry = 0;
    for (int base = 0; base < n; base += 1024){
        int i = base + tid;
        int v = (i < n) ? deg[i] : 0;
        int x = v;
        #pragma unroll
        for (int off = 1; off < 64; off <<= 1){
            int t = __shfl_up(x, off, 64);
            if (lane >= off) x += t;
        }
        if (lane == 63) wsum[wid] = x;
        __syncthreads();
        int wprefix = 0, total = 0;
        #pragma unroll
        for (int j = 0; j < 16; j++){
            int s = wsum[j];
            if (j < wid) wprefix += s;
            total += s;
        }
        int excl = carry + wprefix + (x - v);
        if (i < n){ row_off[i] = excl; cursor[i] = excl; }
        carry += total;
        __syncthreads();
    }
    if (tid == 0) row_off[n] = carry;
}

__global__ void seg_max(const float* sc, const int* dst, unsigned* mkey, int E){
    int i = blockIdx.x * blockDim.x + threadIdx.x;
    if (i < E) atomicMax(&mkey[dst[i]], enc_f(sc[i]));
}

__global__ void seg_exp(const float* sc, const int* dst, const unsigned* mkey,
                        float* ex, float* denom, int E){
    int i = blockIdx.x * blockDim.x + threadIdx.x;
    if (i < E){
        int d = dst[i];
        float v = expf(sc[i] - dec_f(mkey[d]));
        ex[i] = v;
        atomicAdd(&denom[d], v);
    }
}

__global__ void scatter_kernel(const int* src, const int* dst, const float* ex,
                               const float* denom, int* cursor,
                               int* s_src, float* s_alpha, int E){
    int i = blockIdx.x * blockDim.x + threadIdx.x;
    if (i < E){
        int d = dst[i];
        int pos = atomicAdd(&cursor[d], 1);
        s_src[pos] = src[i];
        s_alpha[pos] = ex[i] / denom[d];
    }
}

// one wave per dst node: nf[n] = sum_e alpha_e * hs[src_e] + (sum_e alpha_e) * hd[n]
__global__ __launch_bounds__(256) void agg_csr(const float* hs, const float* hd,
        const int* row_off, const int* s_src, const float* s_alpha,
        float* nf, int n_dst){
    const int w = (blockIdx.x * blockDim.x + threadIdx.x) >> 6;
    const int lane = threadIdx.x & 63;
    if (w >= n_dst) return;
    const int beg = row_off[w], end = row_off[w + 1];
    float2 acc = make_float2(0.f, 0.f);
    float sa = 0.f;
    int e = beg;
    for (; e + 1 < end; e += 2){
        int s0 = s_src[e], s1 = s_src[e + 1];
        float a0 = s_alpha[e], a1 = s_alpha[e + 1];
        float2 v0 = *(const float2*)(hs + (size_t)s0 * DD + lane * 2);
        float2 v1 = *(const float2*)(hs + (size_t)s1 * DD + lane * 2);
        acc.x += a0 * v0.x + a1 * v1.x;
        acc.y += a0 * v0.y + a1 * v1.y;
        sa += a0 + a1;
    }
    if (e < end){
        int s0 = s_src[e];
        float a0 = s_alpha[e];
        float2 v0 = *(const float2*)(hs + (size_t)s0 * DD + lane * 2);
        acc.x += a0 * v0.x; acc.y += a0 * v0.y;
        sa += a0;
    }
    float2 h = *(const float2*)(hd + (size_t)w * DD + lane * 2);
    float2 out;
    out.x = acc.x + sa * h.x;
    out.y = acc.y + sa * h.y;
    *(float2*)(nf + (size_t)w * DD + lane * 2) = out;
}

extern "C" void kernel_launch(void* const* d_in, const int* in_sizes, int n_in,
                              void* d_out, int out_size, void* d_ws, size_t ws_size,
                              hipStream_t stream){
    const float* feat_src = (const float*)d_in[0];
    const float* feat_dst = (const float*)d_in[1];
    const int*   src_idx  = (const int*)d_in[2];
    const int*   dst_idx  = (const int*)d_in[3];
    const float* W_src = (const float*)d_in[4];
    const float* b_src = (const float*)d_in[5];
    const float* W_dst = (const float*)d_in[6];
    const float* b_dst = (const float*)d_in[7];
    const float* W_a1  = (const float*)d_in[8];
    const float* b_a1  = (const float*)d_in[9];
    const float* W_a2  = (const float*)d_in[10];
    const float* b_a2  = (const float*)d_in[11];
    const float* W_out = (const float*)d_in[12];
    const float* b_out = (const float*)d_in[13];
    const int n_src = in_sizes[0] / DD;
    const int n_dst = in_sizes[1] / DD;
    const int E = in_sizes[2];

    // workspace layout (16B alignment maintained; row_off last)
    char* p = (char*)d_ws;
    float* hs = (float*)p;                 p += (size_t)n_src * DD * 4;
    float* hd = (float*)p;                 p += (size_t)n_dst * DD * 4;
    unsigned short* hs_b = (unsigned short*)p; p += (size_t)n_src * DD * 2;
    unsigned short* hd_b = (unsigned short*)p; p += (size_t)n_dst * DD * 2;
    unsigned short* wa1p = (unsigned short*)p; p += 16384 * 2;
    float* sc = (float*)p;                 p += (size_t)E * 4;   // reused as s_alpha
    float* ex = (float*)p;                 p += (size_t)E * 4;
    int* s_src = (int*)p;                  p += (size_t)E * 4;
    unsigned* mkey = (unsigned*)p;         p += (size_t)n_dst * 4;
    float* denom = (float*)p;              p += (size_t)n_dst * 4;
    int* deg = (int*)p;                    p += (size_t)n_dst * 4;
    int* cursor = (int*)p;                 p += (size_t)n_dst * 4;
    int* row_off = (int*)p;                p += ((size_t)n_dst + 1) * 4;
    float* s_alpha = sc;
    float* nf = (float*)d_out;

    init_kernel<<<(n_dst + 255) / 256, 256, 0, stream>>>(mkey, denom, deg, n_dst);
    hist_kernel<<<(E + 255) / 256, 256, 0, stream>>>(dst_idx, deg, E);
    scan_kernel<<<1, 1024, 0, stream>>>(deg, row_off, cursor, n_dst);
    wa1_pack<<<64, 256, 0, stream>>>(W_a1, wa1p);
    tiled_linear<<<(n_src + TILE - 1) / TILE, 256, 0, stream>>>(feat_src, W_src, b_src, hs, hs_b, n_src, 0);
    tiled_linear<<<(n_dst + TILE - 1) / TILE, 256, 0, stream>>>(feat_dst, W_dst, b_dst, hd, hd_b, n_dst, 0);
    edge_score_mfma<<<(E + 127) / 128, 256, 0, stream>>>(hs_b, hd_b, src_idx, dst_idx,
                                                         wa1p, b_a1, W_a2, b_a2, sc, E);
    seg_max<<<(E + 255) / 256, 256, 0, stream>>>(sc, dst_idx, mkey, E);
    seg_exp<<<(E + 255) / 256, 256, 0, stream>>>(sc, dst_idx, mkey, ex, denom, E);
    scatter_kernel<<<(E + 255) / 256, 256, 0, stream>>>(src_idx, dst_idx, ex, denom,
                                                        cursor, s_src, s_alpha, E);
    agg_csr<<<(n_dst * 64 + 255) / 256, 256, 0, stream>>>(hs, hd, row_off, s_src, s_alpha, nf, n_dst);
    tiled_linear<<<(n_dst + TILE - 1) / TILE, 256, 0, stream>>>(nf, W_out, b_out, nf, (unsigned short*)nullptr, n_dst, 1);
}

// Round 4
// 392.688 us; speedup vs baseline: 4.2057x; 1.3261x over previous
//
#include <hip/hip_runtime.h>
#include <math.h>

#define DD 128
#define NEG 0.01f

typedef __attribute__((ext_vector_type(8))) short short8;
typedef __attribute__((ext_vector_type(4))) float f32x4;

__device__ __forceinline__ float lrelu(float x){ return x > 0.f ? x : NEG * x; }

// fp32 -> bf16 round-to-nearest-even (finite inputs)
__device__ __forceinline__ unsigned short f2bf(float f){
    unsigned u = __float_as_uint(f);
    u += 0x7fffu + ((u >> 16) & 1u);
    return (unsigned short)(u >> 16);
}
__device__ __forceinline__ float bf2f(unsigned short h){
    return __uint_as_float(((unsigned)h) << 16);
}

__global__ void init_deg(int* deg, int n_dst){
    int i = blockIdx.x * blockDim.x + threadIdx.x;
    if (i < n_dst) deg[i] = 0;
}

// histogram + per-edge slot assignment in one pass
__global__ void deg_rel(const int* dst, int* deg, int* rel, int E){
    int i = blockIdx.x * blockDim.x + threadIdx.x;
    if (i < E) rel[i] = atomicAdd(&deg[dst[i]], 1);
}

// single-block exclusive scan (int4-vectorized): deg[0..n) -> row_off[0..n]
__global__ __launch_bounds__(1024) void scan_kernel(const int* deg, int* row_off, int n){
    __shared__ int wsum[16];
    const int tid = threadIdx.x;
    const int lane = tid & 63, wid = tid >> 6;
    int carry = 0;
    for (int base = 0; base < n; base += 4096){
        int i4 = base + tid * 4;
        int4 v = make_int4(0, 0, 0, 0);
        if (i4 + 3 < n) v = *(const int4*)(deg + i4);
        else {
            if (i4 + 0 < n) v.x = deg[i4 + 0];
            if (i4 + 1 < n) v.y = deg[i4 + 1];
            if (i4 + 2 < n) v.z = deg[i4 + 2];
            if (i4 + 3 < n) v.w = deg[i4 + 3];
        }
        int tsum = v.x + v.y + v.z + v.w;
        int x = tsum;
        #pragma unroll
        for (int off = 1; off < 64; off <<= 1){
            int t = __shfl_up(x, off, 64);
            if (lane >= off) x += t;
        }
        if (lane == 63) wsum[wid] = x;
        __syncthreads();
        int wprefix = 0, total = 0;
        #pragma unroll
        for (int j = 0; j < 16; j++){
            int s = wsum[j];
            if (j < wid) wprefix += s;
            total += s;
        }
        int excl = carry + wprefix + (x - tsum);
        if (i4 + 3 < n){
            int4 o;
            o.x = excl; o.y = excl + v.x; o.z = o.y + v.y; o.w = o.z + v.z;
            *(int4*)(row_off + i4) = o;
        } else {
            int a = excl;
            if (i4 + 0 < n){ row_off[i4 + 0] = a; a += v.x; }
            if (i4 + 1 < n){ row_off[i4 + 1] = a; a += v.y; }
            if (i4 + 2 < n){ row_off[i4 + 2] = a; a += v.z; }
            if (i4 + 3 < n){ row_off[i4 + 3] = a; }
        }
        carry += total;
        __syncthreads();
    }
    if (tid == 0) row_off[n] = carry;
}

// pack 4 weight matrices into bf16 MFMA B-fragment-linear order.
// seg 0: Wa1 hi; 1,2: Wsrc hi,lo; 3,4: Wdst hi,lo; 5,6: Wout hi,lo
// frag index t: j=t&7, lane=(t>>3)&63, nt=(t>>9)&7, kc=t>>12
// k = kc*32+(lane>>4)*8+j ; n = nt*16+(lane&15)
__global__ void pack_weights(const float* Wa1, const float* Wsrc,
                             const float* Wdst, const float* Wout,
                             unsigned short* out){
    int i = blockIdx.x * blockDim.x + threadIdx.x;   // 7*16384
    if (i >= 7 * 16384) return;
    int seg = i >> 14, t = i & 16383;
    int j = t & 7, lane = (t >> 3) & 63, nt = (t >> 9) & 7, kc = t >> 12;
    int k = kc * 32 + (lane >> 4) * 8 + j;
    int n = nt * 16 + (lane & 15);
    const float* W = (seg == 0) ? Wa1 : (seg <= 2) ? Wsrc : (seg <= 4) ? Wdst : Wout;
    float w = W[k * DD + n];
    unsigned short hi = f2bf(w);
    unsigned short val = hi;
    if (seg == 2 || seg == 4 || seg == 6) val = f2bf(w - bf2f(hi));
    out[i] = val;
}

// Node linear via MFMA, bf16 hi/lo split (~fp32 accuracy).
// Y[r] = act(X[r] @ W + b). 128 rows/block (4 waves x 32 rows).
__global__ __launch_bounds__(256) void lin_mfma(const float* X,
        const unsigned short* Whi, const unsigned short* Wlo, const float* b,
        float* Y, unsigned short* Yb, int nrows, int do_act){
    __shared__ unsigned short sB[2][16384];   // 64 KB
    const int tid = threadIdx.x;
    {
        const uint4* gh = (const uint4*)Whi;
        const uint4* gl = (const uint4*)Wlo;
        uint4* lh = (uint4*)sB[0];
        uint4* ll = (uint4*)sB[1];
        #pragma unroll
        for (int t = 0; t < 8; t++){
            lh[tid + 256 * t] = gh[tid + 256 * t];
            ll[tid + 256 * t] = gl[tid + 256 * t];
        }
    }
    const int wave = tid >> 6, lane = tid & 63;
    const int qd = lane >> 4, ln16 = lane & 15;
    const int row0 = blockIdx.x * 128 + wave * 32;
    int r0 = row0 + ln16;       if (r0 >= nrows) r0 = nrows - 1;
    int r1 = row0 + 16 + ln16;  if (r1 >= nrows) r1 = nrows - 1;
    f32x4 acc[2][8];
    #pragma unroll
    for (int rt = 0; rt < 2; rt++)
        #pragma unroll
        for (int nt = 0; nt < 8; nt++)
            acc[rt][nt] = (f32x4){0.f, 0.f, 0.f, 0.f};
    __syncthreads();
    #pragma unroll
    for (int kc = 0; kc < 4; kc++){
        const int koff = kc * 32 + qd * 8;
        short8 ahi[2], alo[2];
        const float* px[2] = {X + (size_t)r0 * DD + koff, X + (size_t)r1 * DD + koff};
        #pragma unroll
        for (int rt = 0; rt < 2; rt++){
            float4 v0 = *(const float4*)(px[rt]);
            float4 v1 = *(const float4*)(px[rt] + 4);
            float xv[8] = {v0.x, v0.y, v0.z, v0.w, v1.x, v1.y, v1.z, v1.w};
            #pragma unroll
            for (int j = 0; j < 8; j++){
                unsigned short h = f2bf(xv[j]);
                ahi[rt][j] = (short)h;
                alo[rt][j] = (short)f2bf(xv[j] - bf2f(h));
            }
        }
        #pragma unroll
        for (int nt = 0; nt < 8; nt++){
            const int fi = (((kc << 3) + nt) << 6 | lane) << 3;
            short8 bh = *(const short8*)&sB[0][fi];
            short8 bl = *(const short8*)&sB[1][fi];
            #pragma unroll
            for (int rt = 0; rt < 2; rt++){
                acc[rt][nt] = __builtin_amdgcn_mfma_f32_16x16x32_bf16(ahi[rt], bh, acc[rt][nt], 0, 0, 0);
                acc[rt][nt] = __builtin_amdgcn_mfma_f32_16x16x32_bf16(alo[rt], bh, acc[rt][nt], 0, 0, 0);
                acc[rt][nt] = __builtin_amdgcn_mfma_f32_16x16x32_bf16(ahi[rt], bl, acc[rt][nt], 0, 0, 0);
            }
        }
    }
    #pragma unroll
    for (int nt = 0; nt < 8; nt++){
        const int col = nt * 16 + ln16;
        const float bv = b[col];
        #pragma unroll
        for (int rt = 0; rt < 2; rt++){
            #pragma unroll
            for (int r = 0; r < 4; r++){
                int row = row0 + rt * 16 + qd * 4 + r;
                if (row < nrows){
                    float y = acc[rt][nt][r] + bv;
                    if (do_act) y = lrelu(y);
                    Y[(size_t)row * DD + col] = y;
                    if (Yb) Yb[(size_t)row * DD + col] = f2bf(y);
                }
            }
        }
    }
}

// build A-fragment: 8 bf16 of lrelu(hs_row + hd_row)
__device__ __forceinline__ short8 make_afrag(const unsigned short* ph, const unsigned short* pd){
    uint4 a = *(const uint4*)ph;
    uint4 b = *(const uint4*)pd;
    unsigned au[4] = {a.x, a.y, a.z, a.w};
    unsigned bu[4] = {b.x, b.y, b.z, b.w};
    short8 r;
    #pragma unroll
    for (int i = 0; i < 4; i++){
        float h0 = __uint_as_float(au[i] << 16);
        float h1 = __uint_as_float(au[i] & 0xffff0000u);
        float g0 = __uint_as_float(bu[i] << 16);
        float g1 = __uint_as_float(bu[i] & 0xffff0000u);
        float e0 = lrelu(h0 + g0);
        float e1 = lrelu(h1 + g1);
        r[2 * i]     = (short)f2bf(e0);
        r[2 * i + 1] = (short)f2bf(e1);
    }
    return r;
}

// MFMA edge attention score; writes score+src directly into CSR slot.
__global__ __launch_bounds__(256) void edge_score_mfma(
        const unsigned short* hs_b, const unsigned short* hd_b,
        const int* src, const int* dst,
        const unsigned short* wa1p, const float* ba1,
        const float* Wa2, const float* ba2,
        const int* rel, const int* row_off,
        float* s_score, int* s_src, int E){
    __shared__ unsigned short sB[16384];  // 32 KB
    const int tid = threadIdx.x;
    {
        const uint4* g = (const uint4*)wa1p;
        uint4* l = (uint4*)sB;
        #pragma unroll
        for (int t = 0; t < 8; t++) l[tid + 256 * t] = g[tid + 256 * t];
    }
    const int wave = tid >> 6, lane = tid & 63;
    const int qd = lane >> 4, ln16 = lane & 15;
    const int e0 = blockIdx.x * 128 + wave * 32;
    int eid0 = e0 + ln16;       if (eid0 >= E) eid0 = E - 1;
    int eid1 = e0 + 16 + ln16;  if (eid1 >= E) eid1 = E - 1;
    const int s0 = src[eid0], d0 = dst[eid0];
    const int s1 = src[eid1], d1 = dst[eid1];
    f32x4 acc[2][8];
    #pragma unroll
    for (int rt = 0; rt < 2; rt++)
        #pragma unroll
        for (int nt = 0; nt < 8; nt++)
            acc[rt][nt] = (f32x4){0.f, 0.f, 0.f, 0.f};
    __syncthreads();
    #pragma unroll
    for (int kc = 0; kc < 4; kc++){
        const int koff = kc * 32 + qd * 8;
        short8 af0 = make_afrag(hs_b + (size_t)s0 * DD + koff, hd_b + (size_t)d0 * DD + koff);
        short8 af1 = make_afrag(hs_b + (size_t)s1 * DD + koff, hd_b + (size_t)d1 * DD + koff);
        #pragma unroll
        for (int nt = 0; nt < 8; nt++){
            short8 bf = *(const short8*)&sB[(((kc << 3) + nt) << 6 | lane) << 3];
            acc[0][nt] = __builtin_amdgcn_mfma_f32_16x16x32_bf16(af0, bf, acc[0][nt], 0, 0, 0);
            acc[1][nt] = __builtin_amdgcn_mfma_f32_16x16x32_bf16(af1, bf, acc[1][nt], 0, 0, 0);
        }
    }
    float b1v[8], w2v[8];
    #pragma unroll
    for (int nt = 0; nt < 8; nt++){
        b1v[nt] = ba1[nt * 16 + ln16];
        w2v[nt] = Wa2[nt * 16 + ln16];
    }
    const float b2 = ba2[0];
    #pragma unroll
    for (int rt = 0; rt < 2; rt++){
        float p[4] = {0.f, 0.f, 0.f, 0.f};
        #pragma unroll
        for (int nt = 0; nt < 8; nt++)
            #pragma unroll
            for (int r = 0; r < 4; r++){
                float z = acc[rt][nt][r] + b1v[nt];
                z = z > 0.f ? z : NEG * z;
                p[r] += z * w2v[nt];
            }
        #pragma unroll
        for (int r = 0; r < 4; r++){
            float v = p[r];
            #pragma unroll
            for (int off = 1; off < 16; off <<= 1) v += __shfl_xor(v, off, 64);
            p[r] = v;
        }
        if (ln16 == 0){
            int row = e0 + rt * 16 + qd * 4;
            #pragma unroll
            for (int r = 0; r < 4; r++){
                int eid = row + r;
                if (eid < E){
                    int d = dst[eid];
                    int pos = row_off[d] + rel[eid];
                    s_score[pos] = p[r] + b2;
                    s_src[pos] = src[eid];
                }
            }
        }
    }
}

// one wave per dst node: softmax over its CSR segment + weighted aggregation.
// nf[n] = sum_e alpha_e * hs[src_e] + (sum_e alpha_e) * hd[n]
__global__ __launch_bounds__(256) void agg_softmax(const float* hs, const float* hd,
        const int* row_off, const int* s_src, const float* s_score,
        float* nf, int n_dst){
    const int w = (blockIdx.x * blockDim.x + threadIdx.x) >> 6;
    const int lane = threadIdx.x & 63;
    if (w >= n_dst) return;
    const int beg = row_off[w], end = row_off[w + 1];
    // segment max (lanes parallel over edges)
    float m = -INFINITY;
    for (int e = beg + lane; e < end; e += 64) m = fmaxf(m, s_score[e]);
    #pragma unroll
    for (int off = 1; off < 64; off <<= 1) m = fmaxf(m, __shfl_xor(m, off, 64));
    // segment sum of exp
    float sm = 0.f;
    for (int e = beg + lane; e < end; e += 64) sm += expf(s_score[e] - m);
    #pragma unroll
    for (int off = 1; off < 64; off <<= 1) sm += __shfl_xor(sm, off, 64);
    const float inv = (end > beg) ? 1.f / sm : 0.f;
    // weighted gather
    float2 acc = make_float2(0.f, 0.f);
    float sa = 0.f;
    int e = beg;
    for (; e + 1 < end; e += 2){
        float a0 = expf(s_score[e] - m) * inv;
        float a1 = expf(s_score[e + 1] - m) * inv;
        int s0 = s_src[e], s1 = s_src[e + 1];
        float2 v0 = *(const float2*)(hs + (size_t)s0 * DD + lane * 2);
        float2 v1 = *(const float2*)(hs + (size_t)s1 * DD + lane * 2);
        acc.x += a0 * v0.x + a1 * v1.x;
        acc.y += a0 * v0.y + a1 * v1.y;
        sa += a0 + a1;
    }
    if (e < end){
        float a0 = expf(s_score[e] - m) * inv;
        int s0 = s_src[e];
        float2 v0 = *(const float2*)(hs + (size_t)s0 * DD + lane * 2);
        acc.x += a0 * v0.x; acc.y += a0 * v0.y;
        sa += a0;
    }
    float2 h = *(const float2*)(hd + (size_t)w * DD + lane * 2);
    float2 out;
    out.x = acc.x + sa * h.x;
    out.y = acc.y + sa * h.y;
    *(float2*)(nf + (size_t)w * DD + lane * 2) = out;
}

extern "C" void kernel_launch(void* const* d_in, const int* in_sizes, int n_in,
                              void* d_out, int out_size, void* d_ws, size_t ws_size,
                              hipStream_t stream){
    const float* feat_src = (const float*)d_in[0];
    const float* feat_dst = (const float*)d_in[1];
    const int*   src_idx  = (const int*)d_in[2];
    const int*   dst_idx  = (const int*)d_in[3];
    const float* W_src = (const float*)d_in[4];
    const float* b_src = (const float*)d_in[5];
    const float* W_dst = (const float*)d_in[6];
    const float* b_dst = (const float*)d_in[7];
    const float* W_a1  = (const float*)d_in[8];
    const float* b_a1  = (const float*)d_in[9];
    const float* W_a2  = (const float*)d_in[10];
    const float* b_a2  = (const float*)d_in[11];
    const float* W_out = (const float*)d_in[12];
    const float* b_out = (const float*)d_in[13];
    const int n_src = in_sizes[0] / DD;
    const int n_dst = in_sizes[1] / DD;
    const int E = in_sizes[2];

    // workspace layout (all segment sizes multiples of 16 B)
    char* p = (char*)d_ws;
    float* hs = (float*)p;                     p += (size_t)n_src * DD * 4;
    float* hd = (float*)p;                     p += (size_t)n_dst * DD * 4;
    unsigned short* hs_b = (unsigned short*)p; p += (size_t)n_src * DD * 2;
    unsigned short* hd_b = (unsigned short*)p; p += (size_t)n_dst * DD * 2;
    unsigned short* wpack = (unsigned short*)p; p += 7 * 16384 * 2;
    float* s_score = (float*)p;                p += (size_t)E * 4;
    int* s_src = (int*)p;                      p += (size_t)E * 4;
    int* rel = (int*)p;                        p += (size_t)E * 4;
    int* deg = (int*)p;                        p += (size_t)n_dst * 4;
    int* row_off = (int*)p;                    p += ((size_t)n_dst + 1) * 4;
    float* nf = (float*)d_out;

    const unsigned short* wa1p    = wpack;
    const unsigned short* wsrc_hi = wpack + 1 * 16384;
    const unsigned short* wsrc_lo = wpack + 2 * 16384;
    const unsigned short* wdst_hi = wpack + 3 * 16384;
    const unsigned short* wdst_lo = wpack + 4 * 16384;
    const unsigned short* wout_hi = wpack + 5 * 16384;
    const unsigned short* wout_lo = wpack + 6 * 16384;

    init_deg<<<(n_dst + 255) / 256, 256, 0, stream>>>(deg, n_dst);
    deg_rel<<<(E + 255) / 256, 256, 0, stream>>>(dst_idx, deg, rel, E);
    scan_kernel<<<1, 1024, 0, stream>>>(deg, row_off, n_dst);
    pack_weights<<<(7 * 16384 + 255) / 256, 256, 0, stream>>>(W_a1, W_src, W_dst, W_out, wpack);
    lin_mfma<<<(n_src + 127) / 128, 256, 0, stream>>>(feat_src, wsrc_hi, wsrc_lo, b_src,
                                                      hs, hs_b, n_src, 0);
    lin_mfma<<<(n_dst + 127) / 128, 256, 0, stream>>>(feat_dst, wdst_hi, wdst_lo, b_dst,
                                                      hd, hd_b, n_dst, 0);
    edge_score_mfma<<<(E + 127) / 128, 256, 0, stream>>>(hs_b, hd_b, src_idx, dst_idx,
                                                         wa1p, b_a1, W_a2, b_a2,
                                                         rel, row_off, s_score, s_src, E);
    agg_softmax<<<((size_t)n_dst * 64 + 255) / 256, 256, 0, stream>>>(hs, hd, row_off,
                                                                      s_src, s_score, nf, n_dst);
    lin_mfma<<<(n_dst + 127) / 128, 256, 0, stream>>>(nf, wout_hi, wout_lo, b_out,
                                                      nf, (unsigned short*)nullptr, n_dst, 1);
}